// Round 4
// baseline (129.990 us; speedup 1.0000x reference)
//
#include <hip/hip_runtime.h>
#include <hip/hip_bf16.h>

#define BATCH 4096
#define NTOT  8192
#define DIM   512
#define NBLK  2080

typedef __attribute__((ext_vector_type(8))) __bf16 bf16x8;
typedef __attribute__((ext_vector_type(4))) float  floatx4;

__device__ __forceinline__ unsigned short f2bf(float x) {
  union { float f; unsigned u; } v; v.f = x;
  unsigned r = v.u + 0x7fffu + ((v.u >> 16) & 1u);   // RNE
  return (unsigned short)(r >> 16);
}

#define ASYNC16(gp, lp)                                                        \
  __builtin_amdgcn_global_load_lds(                                            \
      (__attribute__((address_space(1))) void*)(gp),                           \
      (__attribute__((address_space(3))) void*)(lp), 16, 0, 0)

// ---------------------------------------------------------------- normalize
// One wave per row: read 512 fp32, rsqrt(sum sq), write 512 bf16.
// Blocks 0..31 also zero S; block 32 zeroes the completion counter.
__global__ __launch_bounds__(256) void nrm_kernel(const float* __restrict__ zi,
                                                  const float* __restrict__ zj,
                                                  ushort* __restrict__ zn,
                                                  float* __restrict__ S,
                                                  int* __restrict__ cnt) {
  if (blockIdx.x < 32) S[blockIdx.x * 256 + threadIdx.x] = 0.0f;
  if (blockIdx.x == 32 && threadIdx.x == 0) *cnt = 0;
  const int row = blockIdx.x * 4 + (threadIdx.x >> 6);
  const int l   = threadIdx.x & 63;
  const float* src = (row < BATCH) ? (zi + (size_t)row * DIM)
                                   : (zj + (size_t)(row - BATCH) * DIM);
  const float4* s4 = (const float4*)src;
  float4 v0 = s4[l];
  float4 v1 = s4[l + 64];
  float ss = v0.x*v0.x + v0.y*v0.y + v0.z*v0.z + v0.w*v0.w
           + v1.x*v1.x + v1.y*v1.y + v1.z*v1.z + v1.w*v1.w;
  #pragma unroll
  for (int m = 1; m < 64; m <<= 1) ss += __shfl_xor(ss, m, 64);
  const float r = 1.0f / fmaxf(sqrtf(ss), 1e-12f);
  ushort4 o0, o1;
  o0.x = f2bf(v0.x * r); o0.y = f2bf(v0.y * r);
  o0.z = f2bf(v0.z * r); o0.w = f2bf(v0.w * r);
  o1.x = f2bf(v1.x * r); o1.y = f2bf(v1.y * r);
  o1.z = f2bf(v1.z * r); o1.w = f2bf(v1.w * r);
  ushort4* d4 = (ushort4*)(zn + (size_t)row * DIM);
  d4[l]      = o0;
  d4[l + 64] = o1;
}

// ---------------------------------------------------------------- main GEMM
// R0-proven loop structure (2-buffer LDS, one __syncthreads per K-iter,
// compiler-scheduled) AND R0's identity block mapping.
// Lessons pinned in code:
//  - NO XCD swizzle here: it cut FETCH 81->62MB but slowed the kernel 20%
//    (R3). This kernel is latency-bound, not BW-bound; contiguous-u-per-XCD
//    concentrates concurrent refills on few panels -> memory-side hotspot.
//  - Completion counter must be RELAXED: agent-scope ACQ_REL RMW emits
//    buffer_wbl2+buffer_inv per block -> L2 invalidate storm (R1/R2,
//    simsum 56->92us). Ordering is structural: __syncthreads drains
//    vmcnt(0), so all sc1 S-adds/P-stores are at the coherence point
//    before the counter bump.
__global__ __launch_bounds__(256) void simsum_kernel(const ushort* __restrict__ zn,
                                                     float* __restrict__ S,
                                                     float* __restrict__ P,
                                                     int* __restrict__ cnt,
                                                     float* __restrict__ out) {
  // identity mapping (R0): u = blockIdx.x
  const int u = blockIdx.x;
  // triangle decode: u = bj*(bj+1)/2 + bi, bi <= bj < 64
  int bj = (int)((sqrtf(8.0f * (float)u + 1.0f) - 1.0f) * 0.5f);
  while ((bj + 1) * (bj + 2) / 2 <= u) ++bj;
  while (bj * (bj + 1) / 2 > u) --bj;
  const int bi = u - bj * (bj + 1) / 2;
  const bool diag = (bi == bj);
  const bool posb = (bj == bi + BATCH / 128);

  __shared__ __align__(16) ushort shA[2 * 4096];
  __shared__ __align__(16) ushort shB[2 * 4096];
  __shared__ float redR[2][128];
  __shared__ float redC[2][128];
  __shared__ float sb[4];
  __shared__ int lastFlag;

  const int t    = threadIdx.x;
  const int w    = t >> 6;
  const int l    = t & 63;
  const int quad = l >> 4;
  const int lo   = l & 15;
  const int wm   = w >> 1;
  const int wn   = w & 1;
  const int tileRow = bi * 128;
  const int tileCol = bj * 128;

  // staging: lane l of wave w stages chunks c0 = w*128+l and c1 = c0+64 into
  // LDS at chunk*16B (wave-uniform base + lane*16). Source k-chunk XOR-swizzled.
  const int c0 = w * 128 + l;
  const int c1 = c0 + 64;
  const int r0 = c0 >> 2, k0 = ((c0 & 3) ^ ((r0 >> 1) & 3)) * 8;
  const int r1 = c1 >> 2, k1 = ((c1 & 3) ^ ((r1 >> 1) & 3)) * 8;
  const ushort* gA0 = zn + (size_t)(tileRow + r0) * DIM + k0;
  const ushort* gA1 = zn + (size_t)(tileRow + r1) * DIM + k1;
  const ushort* gB0 = zn + (size_t)(tileCol + r0) * DIM + k0;
  const ushort* gB1 = zn + (size_t)(tileCol + r1) * DIM + k1;
  ushort* lA0 = shA + w * 1024;
  ushort* lA1 = shA + w * 1024 + 512;
  ushort* lB0 = shB + w * 1024;
  ushort* lB1 = shB + w * 1024 + 512;

  floatx4 acc[4][4];
  #pragma unroll
  for (int i = 0; i < 4; ++i)
    #pragma unroll
    for (int j = 0; j < 4; ++j)
      acc[i][j] = (floatx4){0.f, 0.f, 0.f, 0.f};

  // fragment read offsets (ushorts): chunk = R*4 + (quad ^ ((lo>>1)&3))
  const int sw   = (quad ^ ((lo >> 1) & 3)) * 8;
  const int aOff = (wm * 64 + lo) * 32 + sw;  // + i*512
  const int bOff = (wn * 64 + lo) * 32 + sw;  // + j*512

  // prologue: stage K-tile 0 into buffer 0
  ASYNC16(gA0, lA0); ASYNC16(gA1, lA1);
  ASYNC16(gB0, lB0); ASYNC16(gB1, lB1);
  gA0 += 32; gA1 += 32; gB0 += 32; gB1 += 32;

  #pragma unroll
  for (int it = 0; it < 16; ++it) {
    __syncthreads();  // drains loads for buffer `cur` (issued one iter ago)
    const int co = (it & 1) * 4096;
    const int no = co ^ 4096;
    if (it < 15) {
      ASYNC16(gA0, lA0 + no); ASYNC16(gA1, lA1 + no);
      ASYNC16(gB0, lB0 + no); ASYNC16(gB1, lB1 + no);
      gA0 += 32; gA1 += 32; gB0 += 32; gB1 += 32;
    }
    bf16x8 aF[4], bF[4];
    #pragma unroll
    for (int i = 0; i < 4; ++i) aF[i] = *(const bf16x8*)(shA + co + aOff + i * 512);
    #pragma unroll
    for (int j = 0; j < 4; ++j) bF[j] = *(const bf16x8*)(shB + co + bOff + j * 512);
    #pragma unroll
    for (int i = 0; i < 4; ++i)
      #pragma unroll
      for (int j = 0; j < 4; ++j)
        acc[i][j] = __builtin_amdgcn_mfma_f32_16x16x32_bf16(aF[i], bF[j],
                                                            acc[i][j], 0, 0, 0);
  }

  // ---- epilogue. C/D layout: col = lo, row = quad*4 + r (within 16x16)
  float rs[4][4];
  float cs[4];
  #pragma unroll
  for (int i = 0; i < 4; ++i)
    #pragma unroll
    for (int r = 0; r < 4; ++r) rs[i][r] = 0.f;
  #pragma unroll
  for (int j = 0; j < 4; ++j) cs[j] = 0.f;

  #pragma unroll
  for (int i = 0; i < 4; ++i)
    #pragma unroll
    for (int j = 0; j < 4; ++j)
      #pragma unroll
      for (int r = 0; r < 4; ++r) {
        const float e = __expf(acc[i][j][r] * 10.0f - 10.0f);
        rs[i][r] += e;
        cs[j] += e;
      }

  // block-local diagonal lanes: wm==wn, lo == quad*4 + r  (i.e. quad == lo>>2)
  if (wm == wn && quad == (lo >> 2)) {
    const int r = lo & 3;
    if (diag) {  // self-similarity: remove exp from both row and col sums
      #pragma unroll
      for (int i = 0; i < 4; ++i) {
        const float e = __expf(acc[i][i][r] * 10.0f - 10.0f);
        rs[i][r] -= e;
        cs[i] -= e;
      }
    }
    if (posb) {  // positives: col == row + BATCH. Agent-scope stores: the
      // last-finishing block reads these within this same dispatch, and
      // per-XCD L2s are not coherent for plain stores.
      #pragma unroll
      for (int i = 0; i < 4; ++i) {
        const int row = tileRow + wm * 64 + i * 16 + lo;
        const float v = acc[i][i][r] * 10.0f;
        __hip_atomic_store(&P[row], v, __ATOMIC_RELAXED, __HIP_MEMORY_SCOPE_AGENT);
        __hip_atomic_store(&P[row + BATCH], v, __ATOMIC_RELAXED, __HIP_MEMORY_SCOPE_AGENT);
      }
    }
  }

  // row sums: reduce across the 16 column-lanes (low 4 lane bits)
  #pragma unroll
  for (int m = 1; m < 16; m <<= 1) {
    #pragma unroll
    for (int i = 0; i < 4; ++i)
      #pragma unroll
      for (int r = 0; r < 4; ++r)
        rs[i][r] += __shfl_xor(rs[i][r], m, 64);
  }
  if (lo == 0) {
    #pragma unroll
    for (int i = 0; i < 4; ++i)
      #pragma unroll
      for (int r = 0; r < 4; ++r)
        redR[wn][wm * 64 + i * 16 + quad * 4 + r] = rs[i][r];
  }
  // col sums: reduce across the 4 quads (lane bits 4,5)
  #pragma unroll
  for (int m = 16; m < 64; m <<= 1) {
    #pragma unroll
    for (int j = 0; j < 4; ++j) cs[j] += __shfl_xor(cs[j], m, 64);
  }
  if (quad == 0) {
    #pragma unroll
    for (int j = 0; j < 4; ++j)
      redC[wm][wn * 64 + j * 16 + lo] = cs[j];
  }
  __syncthreads();
  if (t < 128) {
    atomicAdd(&S[tileRow + t], redR[0][t] + redR[1][t]);
  } else if (!diag) {
    const int c = t - 128;
    atomicAdd(&S[tileCol + c], redC[0][c] + redC[1][c]);
  }

  // ---- fused loss: last block to finish computes it.
  // __syncthreads drains this block's atomics (vmcnt(0) before s_barrier),
  // so counter==NBLK-1 implies every S add and P store is globally complete.
  // RELAXED on purpose: ACQ_REL here emits a full per-block L2 wb+inv storm
  // (R1/R2 regression, simsum 56->92us). Do not "strengthen" this.
  __syncthreads();
  if (t == 0) {
    const int old = __hip_atomic_fetch_add(cnt, 1, __ATOMIC_RELAXED,
                                           __HIP_MEMORY_SCOPE_AGENT);
    lastFlag = (old == NBLK - 1);
  }
  __syncthreads();
  if (lastFlag) {
    float a2 = 0.f;
    #pragma unroll 4
    for (int i = t; i < NTOT; i += 256) {
      const float s = __hip_atomic_load(&S[i], __ATOMIC_RELAXED,
                                        __HIP_MEMORY_SCOPE_AGENT);
      const float p = __hip_atomic_load(&P[i], __ATOMIC_RELAXED,
                                        __HIP_MEMORY_SCOPE_AGENT);
      a2 += 10.0f + logf(s) - p;
    }
    #pragma unroll
    for (int m = 1; m < 64; m <<= 1) a2 += __shfl_xor(a2, m, 64);
    if ((t & 63) == 0) sb[t >> 6] = a2;
    __syncthreads();
    if (t == 0)
      out[0] = (sb[0] + sb[1] + sb[2] + sb[3]) * (1.0f / (float)NTOT);
  }
}

extern "C" void kernel_launch(void* const* d_in, const int* in_sizes, int n_in,
                              void* d_out, int out_size, void* d_ws, size_t ws_size,
                              hipStream_t stream) {
  const float* zi = (const float*)d_in[0];
  const float* zj = (const float*)d_in[1];
  ushort* zn = (ushort*)d_ws;                                  // 8192*512 bf16 = 8 MB
  float*  S  = (float*)((char*)d_ws + (size_t)NTOT * DIM * 2); // 32 KB
  float*  P  = S + NTOT;                                       // 32 KB
  int*    cnt = (int*)(P + NTOT);                              // 4 B
  float*  out = (float*)d_out;

  nrm_kernel<<<NTOT / 4, 256, 0, stream>>>(zi, zj, zn, S, cnt);
  simsum_kernel<<<NBLK, 256, 0, stream>>>(zn, S, P, cnt, out);
}

// Round 5
// 116.540 us; speedup vs baseline: 1.1154x; 1.1154x over previous
//
#include <hip/hip_runtime.h>
#include <hip/hip_bf16.h>

#define BATCH 4096
#define NTOT  8192
#define DIM   512
#define NBLK  2080

typedef __attribute__((ext_vector_type(8))) __bf16 bf16x8;
typedef __attribute__((ext_vector_type(4))) float  floatx4;

__device__ __forceinline__ unsigned short f2bf(float x) {
  union { float f; unsigned u; } v; v.f = x;
  unsigned r = v.u + 0x7fffu + ((v.u >> 16) & 1u);   // RNE
  return (unsigned short)(r >> 16);
}

#define ASYNC16(gp, lp)                                                        \
  __builtin_amdgcn_global_load_lds(                                            \
      (__attribute__((address_space(1))) void*)(gp),                           \
      (__attribute__((address_space(3))) void*)(lp), 16, 0, 0)

// ---------------------------------------------------------------- normalize
// One wave per row: read 512 fp32, rsqrt(sum sq), write 512 bf16.
// Blocks 0..31 also zero S; block 32 zeroes out[0] (loss accumulates into it).
__global__ __launch_bounds__(256) void nrm_kernel(const float* __restrict__ zi,
                                                  const float* __restrict__ zj,
                                                  ushort* __restrict__ zn,
                                                  float* __restrict__ S,
                                                  float* __restrict__ out) {
  if (blockIdx.x < 32) S[blockIdx.x * 256 + threadIdx.x] = 0.0f;
  if (blockIdx.x == 32 && threadIdx.x == 0) out[0] = 0.0f;
  const int row = blockIdx.x * 4 + (threadIdx.x >> 6);
  const int l   = threadIdx.x & 63;
  const float* src = (row < BATCH) ? (zi + (size_t)row * DIM)
                                   : (zj + (size_t)(row - BATCH) * DIM);
  const float4* s4 = (const float4*)src;
  float4 v0 = s4[l];
  float4 v1 = s4[l + 64];
  float ss = v0.x*v0.x + v0.y*v0.y + v0.z*v0.z + v0.w*v0.w
           + v1.x*v1.x + v1.y*v1.y + v1.z*v1.z + v1.w*v1.w;
  #pragma unroll
  for (int m = 1; m < 64; m <<= 1) ss += __shfl_xor(ss, m, 64);
  const float r = 1.0f / fmaxf(sqrtf(ss), 1e-12f);
  ushort4 o0, o1;
  o0.x = f2bf(v0.x * r); o0.y = f2bf(v0.y * r);
  o0.z = f2bf(v0.z * r); o0.w = f2bf(v0.w * r);
  o1.x = f2bf(v1.x * r); o1.y = f2bf(v1.y * r);
  o1.z = f2bf(v1.z * r); o1.w = f2bf(v1.w * r);
  ushort4* d4 = (ushort4*)(zn + (size_t)row * DIM);
  d4[l]      = o0;
  d4[l + 64] = o1;
}

// ---------------------------------------------------------------- main GEMM
// EXACT R0 kernel (measured 56.2us / best e2e 123.8). Lessons pinned:
//  - NO fused loss tail: the post-atomic __syncthreads forces a vmcnt(0)
//    drain of the S atomicAdds in every wave + contended counter RMW ->
//    +15us (R3/R4). Waves must retire fire-and-forget after atomicAdd.
//  - NO agent-scope ACQ_REL RMW anywhere: emits buffer_wbl2+buffer_inv,
//    L2 invalidate storm -> +25us (R1/R2).
//  - NO XCD swizzle: +-3us here (latency-bound, not BW-bound regime).
//  - NO sched_barrier/asm-vmcnt pinning of this loop (R1, = learn_hip m141).
__global__ __launch_bounds__(256) void simsum_kernel(const ushort* __restrict__ zn,
                                                     float* __restrict__ S,
                                                     float* __restrict__ P) {
  // triangle decode: u = bj*(bj+1)/2 + bi, bi <= bj < 64
  const int u = blockIdx.x;
  int bj = (int)((sqrtf(8.0f * (float)u + 1.0f) - 1.0f) * 0.5f);
  while ((bj + 1) * (bj + 2) / 2 <= u) ++bj;
  while (bj * (bj + 1) / 2 > u) --bj;
  const int bi = u - bj * (bj + 1) / 2;
  const bool diag = (bi == bj);
  const bool posb = (bj == bi + BATCH / 128);

  __shared__ __align__(16) ushort shA[2 * 4096];
  __shared__ __align__(16) ushort shB[2 * 4096];
  __shared__ float redR[2][128];
  __shared__ float redC[2][128];

  const int t    = threadIdx.x;
  const int w    = t >> 6;
  const int l    = t & 63;
  const int quad = l >> 4;
  const int lo   = l & 15;
  const int wm   = w >> 1;
  const int wn   = w & 1;
  const int tileRow = bi * 128;
  const int tileCol = bj * 128;

  // staging: lane l of wave w stages chunks c0 = w*128+l and c1 = c0+64 into
  // LDS at chunk*16B (wave-uniform base + lane*16). Source k-chunk XOR-swizzled.
  const int c0 = w * 128 + l;
  const int c1 = c0 + 64;
  const int r0 = c0 >> 2, k0 = ((c0 & 3) ^ ((r0 >> 1) & 3)) * 8;
  const int r1 = c1 >> 2, k1 = ((c1 & 3) ^ ((r1 >> 1) & 3)) * 8;
  const ushort* gA0 = zn + (size_t)(tileRow + r0) * DIM + k0;
  const ushort* gA1 = zn + (size_t)(tileRow + r1) * DIM + k1;
  const ushort* gB0 = zn + (size_t)(tileCol + r0) * DIM + k0;
  const ushort* gB1 = zn + (size_t)(tileCol + r1) * DIM + k1;
  ushort* lA0 = shA + w * 1024;
  ushort* lA1 = shA + w * 1024 + 512;
  ushort* lB0 = shB + w * 1024;
  ushort* lB1 = shB + w * 1024 + 512;

  floatx4 acc[4][4];
  #pragma unroll
  for (int i = 0; i < 4; ++i)
    #pragma unroll
    for (int j = 0; j < 4; ++j)
      acc[i][j] = (floatx4){0.f, 0.f, 0.f, 0.f};

  // fragment read offsets (ushorts): chunk = R*4 + (quad ^ ((lo>>1)&3))
  const int sw   = (quad ^ ((lo >> 1) & 3)) * 8;
  const int aOff = (wm * 64 + lo) * 32 + sw;  // + i*512
  const int bOff = (wn * 64 + lo) * 32 + sw;  // + j*512

  // prologue: stage K-tile 0 into buffer 0
  ASYNC16(gA0, lA0); ASYNC16(gA1, lA1);
  ASYNC16(gB0, lB0); ASYNC16(gB1, lB1);
  gA0 += 32; gA1 += 32; gB0 += 32; gB1 += 32;

  #pragma unroll
  for (int it = 0; it < 16; ++it) {
    __syncthreads();  // drains loads for buffer `cur` (issued one iter ago)
    const int co = (it & 1) * 4096;
    const int no = co ^ 4096;
    if (it < 15) {
      ASYNC16(gA0, lA0 + no); ASYNC16(gA1, lA1 + no);
      ASYNC16(gB0, lB0 + no); ASYNC16(gB1, lB1 + no);
      gA0 += 32; gA1 += 32; gB0 += 32; gB1 += 32;
    }
    bf16x8 aF[4], bF[4];
    #pragma unroll
    for (int i = 0; i < 4; ++i) aF[i] = *(const bf16x8*)(shA + co + aOff + i * 512);
    #pragma unroll
    for (int j = 0; j < 4; ++j) bF[j] = *(const bf16x8*)(shB + co + bOff + j * 512);
    #pragma unroll
    for (int i = 0; i < 4; ++i)
      #pragma unroll
      for (int j = 0; j < 4; ++j)
        acc[i][j] = __builtin_amdgcn_mfma_f32_16x16x32_bf16(aF[i], bF[j],
                                                            acc[i][j], 0, 0, 0);
  }

  // ---- epilogue. C/D layout: col = lo, row = quad*4 + r (within 16x16)
  float rs[4][4];
  float cs[4];
  #pragma unroll
  for (int i = 0; i < 4; ++i)
    #pragma unroll
    for (int r = 0; r < 4; ++r) rs[i][r] = 0.f;
  #pragma unroll
  for (int j = 0; j < 4; ++j) cs[j] = 0.f;

  #pragma unroll
  for (int i = 0; i < 4; ++i)
    #pragma unroll
    for (int j = 0; j < 4; ++j)
      #pragma unroll
      for (int r = 0; r < 4; ++r) {
        const float e = __expf(acc[i][j][r] * 10.0f - 10.0f);
        rs[i][r] += e;
        cs[j] += e;
      }

  // block-local diagonal lanes: wm==wn, lo == quad*4 + r  (i.e. quad == lo>>2)
  if (wm == wn && quad == (lo >> 2)) {
    const int r = lo & 3;
    if (diag) {  // self-similarity: remove exp from both row and col sums
      #pragma unroll
      for (int i = 0; i < 4; ++i) {
        const float e = __expf(acc[i][i][r] * 10.0f - 10.0f);
        rs[i][r] -= e;
        cs[i] -= e;
      }
    }
    if (posb) {  // positives: col == row + BATCH
      #pragma unroll
      for (int i = 0; i < 4; ++i) {
        const int row = tileRow + wm * 64 + i * 16 + lo;
        const float v = acc[i][i][r] * 10.0f;
        P[row] = v;
        P[row + BATCH] = v;
      }
    }
  }

  // row sums: reduce across the 16 column-lanes (low 4 lane bits)
  #pragma unroll
  for (int m = 1; m < 16; m <<= 1) {
    #pragma unroll
    for (int i = 0; i < 4; ++i)
      #pragma unroll
      for (int r = 0; r < 4; ++r)
        rs[i][r] += __shfl_xor(rs[i][r], m, 64);
  }
  if (lo == 0) {
    #pragma unroll
    for (int i = 0; i < 4; ++i)
      #pragma unroll
      for (int r = 0; r < 4; ++r)
        redR[wn][wm * 64 + i * 16 + quad * 4 + r] = rs[i][r];
  }
  // col sums: reduce across the 4 quads (lane bits 4,5)
  #pragma unroll
  for (int m = 16; m < 64; m <<= 1) {
    #pragma unroll
    for (int j = 0; j < 4; ++j) cs[j] += __shfl_xor(cs[j], m, 64);
  }
  if (quad == 0) {
    #pragma unroll
    for (int j = 0; j < 4; ++j)
      redC[wm][wn * 64 + j * 16 + lo] = cs[j];
  }
  __syncthreads();
  if (t < 128) {
    atomicAdd(&S[tileRow + t], redR[0][t] + redR[1][t]);
  } else if (!diag) {
    const int c = t - 128;
    atomicAdd(&S[tileCol + c], redC[0][c] + redC[1][c]);
  }
  // waves retire here, fire-and-forget on the atomics (no drain — critical).
}

// ---------------------------------------------------------------- final loss
// 32 blocks x 256 threads, 1 element/thread (R0's single-block version was
// latency-bound: 32 dependent ~600cy iterations -> ~10us; this is ~2us).
// Partial per block, one float atomicAdd into out[0] (zeroed by nrm; same
// float-atomic accumulation pattern S already uses).
__global__ __launch_bounds__(256) void loss_kernel(const float* __restrict__ S,
                                                   const float* __restrict__ P,
                                                   float* __restrict__ out) {
  const int i = blockIdx.x * 256 + threadIdx.x;
  float a = 10.0f + logf(S[i]) - P[i];
  #pragma unroll
  for (int m = 1; m < 64; m <<= 1) a += __shfl_xor(a, m, 64);
  __shared__ float sb[4];
  if ((threadIdx.x & 63) == 0) sb[threadIdx.x >> 6] = a;
  __syncthreads();
  if (threadIdx.x == 0)
    atomicAdd(out, (sb[0] + sb[1] + sb[2] + sb[3]) * (1.0f / (float)NTOT));
}

extern "C" void kernel_launch(void* const* d_in, const int* in_sizes, int n_in,
                              void* d_out, int out_size, void* d_ws, size_t ws_size,
                              hipStream_t stream) {
  const float* zi = (const float*)d_in[0];
  const float* zj = (const float*)d_in[1];
  ushort* zn = (ushort*)d_ws;                                  // 8192*512 bf16 = 8 MB
  float*  S  = (float*)((char*)d_ws + (size_t)NTOT * DIM * 2); // 32 KB
  float*  P  = S + NTOT;                                       // 32 KB
  float*  out = (float*)d_out;

  nrm_kernel<<<NTOT / 4, 256, 0, stream>>>(zi, zj, zn, S, out);
  simsum_kernel<<<NBLK, 256, 0, stream>>>(zn, S, P);
  loss_kernel<<<NTOT / 256, 256, 0, stream>>>(S, P, out);
}

// Round 6
// 115.496 us; speedup vs baseline: 1.1255x; 1.0090x over previous
//
#include <hip/hip_runtime.h>
#include <hip/hip_bf16.h>

#define BATCH 4096
#define NTOT  8192
#define DIM   512
#define NBLK  2080

typedef __attribute__((ext_vector_type(8))) __bf16 bf16x8;
typedef __attribute__((ext_vector_type(4))) float  floatx4;

__device__ __forceinline__ unsigned short f2bf(float x) {
  union { float f; unsigned u; } v; v.f = x;
  unsigned r = v.u + 0x7fffu + ((v.u >> 16) & 1u);   // RNE
  return (unsigned short)(r >> 16);
}

#define ASYNC16(gp, lp)                                                        \
  __builtin_amdgcn_global_load_lds(                                            \
      (__attribute__((address_space(1))) void*)(gp),                           \
      (__attribute__((address_space(3))) void*)(lp), 16, 0, 0)

// ---------------------------------------------------------------- normalize
// One wave per row: read 512 fp32, rsqrt(sum sq), write 512 bf16.
// Blocks 0..31 also zero S; block 32 zeroes out[0] (loss accumulates into it).
__global__ __launch_bounds__(256) void nrm_kernel(const float* __restrict__ zi,
                                                  const float* __restrict__ zj,
                                                  ushort* __restrict__ zn,
                                                  float* __restrict__ S,
                                                  float* __restrict__ out) {
  if (blockIdx.x < 32) S[blockIdx.x * 256 + threadIdx.x] = 0.0f;
  if (blockIdx.x == 32 && threadIdx.x == 0) out[0] = 0.0f;
  const int row = blockIdx.x * 4 + (threadIdx.x >> 6);
  const int l   = threadIdx.x & 63;
  const float* src = (row < BATCH) ? (zi + (size_t)row * DIM)
                                   : (zj + (size_t)(row - BATCH) * DIM);
  const float4* s4 = (const float4*)src;
  float4 v0 = s4[l];
  float4 v1 = s4[l + 64];
  float ss = v0.x*v0.x + v0.y*v0.y + v0.z*v0.z + v0.w*v0.w
           + v1.x*v1.x + v1.y*v1.y + v1.z*v1.z + v1.w*v1.w;
  #pragma unroll
  for (int m = 1; m < 64; m <<= 1) ss += __shfl_xor(ss, m, 64);
  const float r = 1.0f / fmaxf(sqrtf(ss), 1e-12f);
  ushort4 o0, o1;
  o0.x = f2bf(v0.x * r); o0.y = f2bf(v0.y * r);
  o0.z = f2bf(v0.z * r); o0.w = f2bf(v0.w * r);
  o1.x = f2bf(v1.x * r); o1.y = f2bf(v1.y * r);
  o1.z = f2bf(v1.z * r); o1.w = f2bf(v1.w * r);
  ushort4* d4 = (ushort4*)(zn + (size_t)row * DIM);
  d4[l]      = o0;
  d4[l + 64] = o1;
}

// ---------------------------------------------------------------- main GEMM
// R5 kernel + depth-2 staging pipeline (3 LDS buffers, counted vmcnt).
// CLEAN version of R1's schedule: NO sched_barrier(0), NO setprio — those
// were bundled in R1 (m141-style compiler degradation). The asm vmcnt has a
// "memory" clobber so LDS reads cannot hoist above it; raw s_barrier keeps
// LDS ops ordered. WAR-safe: stage(it+2) writes the buffer last read at
// iter it-1, and those reads completed before barrier(it).
// Lessons still pinned:
//  - NO fused loss tail (+15us, R3/R4). Waves retire fire-and-forget.
//  - NO agent-scope ACQ_REL RMW (L2 invalidate storm, +25us, R1/R2).
//  - NO XCD swizzle (+-3us, wrong regime).
__global__ __launch_bounds__(256) void simsum_kernel(const ushort* __restrict__ zn,
                                                     float* __restrict__ S,
                                                     float* __restrict__ P) {
  // triangle decode: u = bj*(bj+1)/2 + bi, bi <= bj < 64
  const int u = blockIdx.x;
  int bj = (int)((sqrtf(8.0f * (float)u + 1.0f) - 1.0f) * 0.5f);
  while ((bj + 1) * (bj + 2) / 2 <= u) ++bj;
  while (bj * (bj + 1) / 2 > u) --bj;
  const int bi = u - bj * (bj + 1) / 2;
  const bool diag = (bi == bj);
  const bool posb = (bj == bi + BATCH / 128);

  __shared__ __align__(16) ushort shA[3 * 4096];
  __shared__ __align__(16) ushort shB[3 * 4096];
  __shared__ float redR[2][128];
  __shared__ float redC[2][128];

  const int t    = threadIdx.x;
  const int w    = t >> 6;
  const int l    = t & 63;
  const int quad = l >> 4;
  const int lo   = l & 15;
  const int wm   = w >> 1;
  const int wn   = w & 1;
  const int tileRow = bi * 128;
  const int tileCol = bj * 128;

  // staging: lane l of wave w stages chunks c0 = w*128+l and c1 = c0+64 into
  // LDS at chunk*16B (wave-uniform base + lane*16). Source k-chunk XOR-swizzled.
  const int c0 = w * 128 + l;
  const int c1 = c0 + 64;
  const int r0 = c0 >> 2, k0 = ((c0 & 3) ^ ((r0 >> 1) & 3)) * 8;
  const int r1 = c1 >> 2, k1 = ((c1 & 3) ^ ((r1 >> 1) & 3)) * 8;
  const ushort* gA0 = zn + (size_t)(tileRow + r0) * DIM + k0;
  const ushort* gA1 = zn + (size_t)(tileRow + r1) * DIM + k1;
  const ushort* gB0 = zn + (size_t)(tileCol + r0) * DIM + k0;
  const ushort* gB1 = zn + (size_t)(tileCol + r1) * DIM + k1;
  ushort* lA0 = shA + w * 1024;
  ushort* lA1 = shA + w * 1024 + 512;
  ushort* lB0 = shB + w * 1024;
  ushort* lB1 = shB + w * 1024 + 512;

  floatx4 acc[4][4];
  #pragma unroll
  for (int i = 0; i < 4; ++i)
    #pragma unroll
    for (int j = 0; j < 4; ++j)
      acc[i][j] = (floatx4){0.f, 0.f, 0.f, 0.f};

  // fragment read offsets (ushorts): chunk = R*4 + (quad ^ ((lo>>1)&3))
  const int sw   = (quad ^ ((lo >> 1) & 3)) * 8;
  const int aOff = (wm * 64 + lo) * 32 + sw;  // + i*512
  const int bOff = (wn * 64 + lo) * 32 + sw;  // + j*512

  #define STAGE(bufo)                                                         \
    ASYNC16(gA0, lA0 + (bufo)); ASYNC16(gA1, lA1 + (bufo));                   \
    ASYNC16(gB0, lB0 + (bufo)); ASYNC16(gB1, lB1 + (bufo));                   \
    gA0 += 32; gA1 += 32; gB0 += 32; gB1 += 32;

  // prologue: K-tiles 0,1 into buffers 0,1 (8 loads/thread in flight)
  STAGE(0)
  STAGE(4096)

  #pragma unroll
  for (int it = 0; it < 16; ++it) {
    // Wait for tile `it`'s 4 loads only; tile it+1's stay in flight across
    // the barrier. Every thread waits before the barrier -> buffer valid.
    if (it < 15) asm volatile("s_waitcnt vmcnt(4)" ::: "memory");
    else         asm volatile("s_waitcnt vmcnt(0)" ::: "memory");
    __builtin_amdgcn_s_barrier();
    if (it < 14) {
      const int nb = ((it + 2) % 3) * 4096;  // constant under full unroll
      STAGE(nb)
    }
    const int co = (it % 3) * 4096;
    bf16x8 aF[4], bF[4];
    #pragma unroll
    for (int i = 0; i < 4; ++i) aF[i] = *(const bf16x8*)(shA + co + aOff + i * 512);
    #pragma unroll
    for (int j = 0; j < 4; ++j) bF[j] = *(const bf16x8*)(shB + co + bOff + j * 512);
    #pragma unroll
    for (int i = 0; i < 4; ++i)
      #pragma unroll
      for (int j = 0; j < 4; ++j)
        acc[i][j] = __builtin_amdgcn_mfma_f32_16x16x32_bf16(aF[i], bF[j],
                                                            acc[i][j], 0, 0, 0);
  }
  #undef STAGE

  // ---- epilogue. C/D layout: col = lo, row = quad*4 + r (within 16x16)
  float rs[4][4];
  float cs[4];
  #pragma unroll
  for (int i = 0; i < 4; ++i)
    #pragma unroll
    for (int r = 0; r < 4; ++r) rs[i][r] = 0.f;
  #pragma unroll
  for (int j = 0; j < 4; ++j) cs[j] = 0.f;

  #pragma unroll
  for (int i = 0; i < 4; ++i)
    #pragma unroll
    for (int j = 0; j < 4; ++j)
      #pragma unroll
      for (int r = 0; r < 4; ++r) {
        const float e = __expf(acc[i][j][r] * 10.0f - 10.0f);
        rs[i][r] += e;
        cs[j] += e;
      }

  // block-local diagonal lanes: wm==wn, lo == quad*4 + r  (i.e. quad == lo>>2)
  if (wm == wn && quad == (lo >> 2)) {
    const int r = lo & 3;
    if (diag) {  // self-similarity: remove exp from both row and col sums
      #pragma unroll
      for (int i = 0; i < 4; ++i) {
        const float e = __expf(acc[i][i][r] * 10.0f - 10.0f);
        rs[i][r] -= e;
        cs[i] -= e;
      }
    }
    if (posb) {  // positives: col == row + BATCH
      #pragma unroll
      for (int i = 0; i < 4; ++i) {
        const int row = tileRow + wm * 64 + i * 16 + lo;
        const float v = acc[i][i][r] * 10.0f;
        P[row] = v;
        P[row + BATCH] = v;
      }
    }
  }

  // row sums: reduce across the 16 column-lanes (low 4 lane bits)
  #pragma unroll
  for (int m = 1; m < 16; m <<= 1) {
    #pragma unroll
    for (int i = 0; i < 4; ++i)
      #pragma unroll
      for (int r = 0; r < 4; ++r)
        rs[i][r] += __shfl_xor(rs[i][r], m, 64);
  }
  if (lo == 0) {
    #pragma unroll
    for (int i = 0; i < 4; ++i)
      #pragma unroll
      for (int r = 0; r < 4; ++r)
        redR[wn][wm * 64 + i * 16 + quad * 4 + r] = rs[i][r];
  }
  // col sums: reduce across the 4 quads (lane bits 4,5)
  #pragma unroll
  for (int m = 16; m < 64; m <<= 1) {
    #pragma unroll
    for (int j = 0; j < 4; ++j) cs[j] += __shfl_xor(cs[j], m, 64);
  }
  if (quad == 0) {
    #pragma unroll
    for (int j = 0; j < 4; ++j)
      redC[wm][wn * 64 + j * 16 + lo] = cs[j];
  }
  __syncthreads();
  if (t < 128) {
    atomicAdd(&S[tileRow + t], redR[0][t] + redR[1][t]);
  } else if (!diag) {
    const int c = t - 128;
    atomicAdd(&S[tileCol + c], redC[0][c] + redC[1][c]);
  }
  // waves retire here, fire-and-forget on the atomics (no drain — critical).
}

// ---------------------------------------------------------------- final loss
// 32 blocks x 256 threads, 1 element/thread; partial per block, one float
// atomicAdd into out[0] (zeroed by nrm).
__global__ __launch_bounds__(256) void loss_kernel(const float* __restrict__ S,
                                                   const float* __restrict__ P,
                                                   float* __restrict__ out) {
  const int i = blockIdx.x * 256 + threadIdx.x;
  float a = 10.0f + logf(S[i]) - P[i];
  #pragma unroll
  for (int m = 1; m < 64; m <<= 1) a += __shfl_xor(a, m, 64);
  __shared__ float sb[4];
  if ((threadIdx.x & 63) == 0) sb[threadIdx.x >> 6] = a;
  __syncthreads();
  if (threadIdx.x == 0)
    atomicAdd(out, (sb[0] + sb[1] + sb[2] + sb[3]) * (1.0f / (float)NTOT));
}

extern "C" void kernel_launch(void* const* d_in, const int* in_sizes, int n_in,
                              void* d_out, int out_size, void* d_ws, size_t ws_size,
                              hipStream_t stream) {
  const float* zi = (const float*)d_in[0];
  const float* zj = (const float*)d_in[1];
  ushort* zn = (ushort*)d_ws;                                  // 8192*512 bf16 = 8 MB
  float*  S  = (float*)((char*)d_ws + (size_t)NTOT * DIM * 2); // 32 KB
  float*  P  = S + NTOT;                                       // 32 KB
  float*  out = (float*)d_out;

  nrm_kernel<<<NTOT / 4, 256, 0, stream>>>(zi, zj, zn, S, out);
  simsum_kernel<<<NBLK, 256, 0, stream>>>(zn, S, P);
  loss_kernel<<<NTOT / 256, 256, 0, stream>>>(S, P, out);
}